// Round 13
// baseline (701.669 us; speedup 1.0000x reference)
//
#include <hip/hip_runtime.h>
#include <math.h>

// GCN, R13: scatter-side aggregation into per-bucket LDS (edges already
// bucket-grouped by k_part) -- the counting sort is GONE. One 1024-thread
// block per 256-node bucket: LDS rows init with self term, flat edge loop
// (8 lanes/edge: 1 float4 gather + 4 ds_add, no divergence), barrier,
// in-block transform (LDS broadcast reads x register weights).
// u rows fp32, stride 32 floats (128B). eb packed (src<<8)|(dst&255).
// LDS row stride 36 floats to spread ds_add banks.

#define TPB 256
#define LTPB 1024             // layer kernels: 16 waves/block
#define BSH 8                 // 256 nodes per bucket
#define BNODES 256
#define MAXBUCK 512
#define CH 4096               // edges per partition block
#define CAPSH 13              // slab capacity 8192 entries/bucket
#define CAP (1 << CAPSH)
#define LSTR 36               // LDS row stride (floats)

// partition edges into per-bucket slabs; bcursor RELATIVE (memset 0).
__global__ void k_part(const int* __restrict__ src, const int* __restrict__ dst,
                       int* __restrict__ bcursor, int* __restrict__ eb,
                       int E, int nbuck) {
    __shared__ int lh[MAXBUCK];
    __shared__ int lbase[MAXBUCK];
    int t = threadIdx.x;
    int chunk0 = blockIdx.x * CH;
    int end = min(chunk0 + CH, E);
    const int4* dst4 = (const int4*)dst;
    const int4* src4 = (const int4*)src;
    for (int i = t; i < nbuck; i += TPB) lh[i] = 0;
    __syncthreads();
    for (int e4 = chunk0 / 4 + t; e4 * 4 < end; e4 += TPB) {
        int base = e4 * 4;
        int4 d = dst4[e4];
        if (base + 0 < end) atomicAdd(&lh[d.x >> BSH], 1);
        if (base + 1 < end) atomicAdd(&lh[d.y >> BSH], 1);
        if (base + 2 < end) atomicAdd(&lh[d.z >> BSH], 1);
        if (base + 3 < end) atomicAdd(&lh[d.w >> BSH], 1);
    }
    __syncthreads();
    for (int i = t; i < nbuck; i += TPB) {
        int c = lh[i];
        lbase[i] = c ? atomicAdd(&bcursor[i], c) : 0;
        lh[i] = 0;
    }
    __syncthreads();
    for (int e4 = chunk0 / 4 + t; e4 * 4 < end; e4 += TPB) {
        int base = e4 * 4;
        int4 d = dst4[e4];
        int4 s = src4[e4];
        #define PUT(c, sv) if (base + c < end) { \
            int b = (d.sv) >> BSH; \
            int r = lbase[b] + atomicAdd(&lh[b], 1); \
            if (r < CAP) \
                eb[((size_t)b << CAPSH) + r] = ((s.sv) << BSH) | ((d.sv) & (BNODES - 1)); }
        PUT(0, x) PUT(1, y) PUT(2, z) PUT(3, w)
        #undef PUT
    }
}

// per bucket: LDS histogram of local dst -> dinv, plus u1f = x*dinv rows
// (stride 32 floats, features 18..31 zeroed). No sort.
__global__ void k_prep(const int* __restrict__ eb, const int* __restrict__ bcursor,
                       const float* __restrict__ x, float* __restrict__ dinv,
                       float* __restrict__ u1f, int n) {
    __shared__ int lcnt[BNODES];
    __shared__ float ldinv[BNODES];
    int b = blockIdx.x;
    int t = threadIdx.x;
    int node0 = b << BSH;
    int beg = b << CAPSH;
    int end = beg + min(bcursor[b], CAP);
    lcnt[t] = 0;
    __syncthreads();
    for (int i = beg + t; i < end; i += TPB)
        atomicAdd(&lcnt[eb[i] & (BNODES - 1)], 1);
    __syncthreads();
    int node = node0 + t;
    float dv = rsqrtf(1.0f + (float)lcnt[t]);
    ldinv[t] = dv;
    if (node < n) dinv[node] = dv;
    __syncthreads();
    int nn = min(BNODES, n - node0);
    int tot = nn * 32;
    const float* xb = x + (size_t)node0 * 18;
    float* ub = u1f + (size_t)node0 * 32;
    for (int i = t; i < tot; i += TPB) {
        int nl = i >> 5, f = i & 31;
        ub[i] = (f < 18) ? xb[nl * 18 + f] * ldinv[nl] : 0.f;
    }
}

// layer 1: one block per bucket. LDS agg (ds_add) -> transform -> u2f rows.
__global__ void __launch_bounds__(LTPB, 1)
k_layer1(const float4* __restrict__ u1q, const int* __restrict__ eb,
         const int* __restrict__ bcursor, const float* __restrict__ dinv,
         const float* __restrict__ W1, const float* __restrict__ b1,
         float* __restrict__ u2f, int n) {
    __shared__ float lagg[BNODES][LSTR];
    int b = blockIdx.x;
    int t = threadIdx.x;
    int lane = t & 63, wv = t >> 6;           // 16 waves
    int q = lane & 7, g = lane >> 3;          // 8 groups of 8 lanes
    int h = lane >> 5, f = lane & 31;
    int node0 = b << BSH;
    // init LDS rows with self term
    for (int i = t; i < BNODES * 32; i += LTPB) {
        int nl = i >> 5, ff = i & 31;
        int node = node0 + nl;
        lagg[nl][ff] = (node < n) ? ((const float*)u1q)[(size_t)node * 32 + ff] : 0.f;
    }
    float w1r[18];
#pragma unroll
    for (int k = 0; k < 18; ++k) w1r[k] = W1[k * 32 + f];
    float b1v = b1[f];
    __syncthreads();
    // flat edge loop: wave wv takes 8 edges per pass, stride 16*8
    int nE = min(bcursor[b], CAP);
    const int* ebb = eb + ((size_t)b << CAPSH);
    for (int base = wv * 8; base < nE; base += 16 * 8) {
        int e = base + g;
        if (e < nE) {
            int pk = ebb[e];
            int s = pk >> BSH, d = pk & (BNODES - 1);
            float4 v = u1q[(size_t)s * 8 + q];
            atomicAdd(&lagg[d][4 * q + 0], v.x);
            atomicAdd(&lagg[d][4 * q + 1], v.y);
            atomicAdd(&lagg[d][4 * q + 2], v.z);
            atomicAdd(&lagg[d][4 * q + 3], v.w);
        }
    }
    __syncthreads();
    // transform: half-wave per node; 32 nodes per pass, 8 passes
#pragma unroll
    for (int r = 0; r < 8; ++r) {
        int nl = r * 32 + wv * 2 + h;
        int node = node0 + nl;
        if (node < n) {
            float a = 0.f;
#pragma unroll
            for (int k = 0; k < 18; ++k) a = fmaf(lagg[nl][k], w1r[k], a);
            float di = dinv[node];
            u2f[(size_t)node * 32 + f] = fmaxf(fmaf(di, a, b1v), 0.f) * di;
        }
    }
}

// layer 2 + head: same agg structure; transform lane = output (W2 col in
// 32 VGPRs), FC(64->2) butterfly + log_softmax.
__global__ void __launch_bounds__(LTPB, 1)
k_layer2(const float4* __restrict__ u2q, const int* __restrict__ eb,
         const int* __restrict__ bcursor, const float* __restrict__ dinv,
         const float* __restrict__ W2, const float* __restrict__ b2,
         const float* __restrict__ Wfc, const float* __restrict__ bfc,
         float* __restrict__ out, int n) {
    __shared__ float lagg[BNODES][LSTR];
    int b = blockIdx.x;
    int t = threadIdx.x;
    int lane = t & 63, wv = t >> 6;
    int q = lane & 7, g = lane >> 3;
    int node0 = b << BSH;
    for (int i = t; i < BNODES * 32; i += LTPB) {
        int nl = i >> 5, ff = i & 31;
        int node = node0 + nl;
        lagg[nl][ff] = (node < n) ? ((const float*)u2q)[(size_t)node * 32 + ff] : 0.f;
    }
    float w2r[32];
#pragma unroll
    for (int k = 0; k < 32; ++k) w2r[k] = W2[k * 64 + lane];
    float b2v = b2[lane];
    float wf0 = Wfc[lane * 2 + 0], wf1 = Wfc[lane * 2 + 1];
    float bf0 = bfc[0], bf1 = bfc[1];
    __syncthreads();
    int nE = min(bcursor[b], CAP);
    const int* ebb = eb + ((size_t)b << CAPSH);
    for (int base = wv * 8; base < nE; base += 16 * 8) {
        int e = base + g;
        if (e < nE) {
            int pk = ebb[e];
            int s = pk >> BSH, d = pk & (BNODES - 1);
            float4 v = u2q[(size_t)s * 8 + q];
            atomicAdd(&lagg[d][4 * q + 0], v.x);
            atomicAdd(&lagg[d][4 * q + 1], v.y);
            atomicAdd(&lagg[d][4 * q + 2], v.z);
            atomicAdd(&lagg[d][4 * q + 3], v.w);
        }
    }
    __syncthreads();
    // transform: one node per wave per pass; 16 passes
#pragma unroll 4
    for (int r = 0; r < 16; ++r) {
        int nl = r * 16 + wv;
        int node = node0 + nl;
        float c0 = 0.f, c1 = 0.f, c2 = 0.f, c3 = 0.f;
#pragma unroll
        for (int k = 0; k < 32; k += 4) {
            c0 = fmaf(lagg[nl][k],     w2r[k],     c0);
            c1 = fmaf(lagg[nl][k + 1], w2r[k + 1], c1);
            c2 = fmaf(lagg[nl][k + 2], w2r[k + 2], c2);
            c3 = fmaf(lagg[nl][k + 3], w2r[k + 3], c3);
        }
        float a = (c0 + c1) + (c2 + c3);
        float v = (node < n) ? fmaxf(fmaf(dinv[node], a, b2v), 0.f) : 0.f;
        float l0 = v * wf0;
        float l1 = v * wf1;
#pragma unroll
        for (int off = 32; off >= 1; off >>= 1) {
            l0 += __shfl_xor(l0, off, 64);
            l1 += __shfl_xor(l1, off, 64);
        }
        if (lane == 0 && node < n) {
            l0 += bf0;
            l1 += bf1;
            float m2 = fmaxf(l0, l1);
            float lse = m2 + logf(expf(l0 - m2) + expf(l1 - m2));
            out[node * 2 + 0] = l0 - lse;
            out[node * 2 + 1] = l1 - lse;
        }
    }
}

extern "C" void kernel_launch(void* const* d_in, const int* in_sizes, int n_in,
                              void* d_out, int out_size, void* d_ws, size_t ws_size,
                              hipStream_t stream) {
    const float* x   = (const float*)d_in[0];
    const int*   ei  = (const int*)d_in[1];
    const float* W1  = (const float*)d_in[2];
    const float* b1  = (const float*)d_in[3];
    const float* W2  = (const float*)d_in[4];
    const float* b2  = (const float*)d_in[5];
    const float* Wfc = (const float*)d_in[6];
    const float* bfc = (const float*)d_in[7];
    float* out = (float*)d_out;

    const int n = in_sizes[0] / 18;
    const int E = in_sizes[1] / 2;
    const int* src = ei;
    const int* dst = ei + E;
    const int nbuck = (n + BNODES - 1) >> BSH;

    // ws: bcursor[nbuck] | dinv[n] | eb[nbuck*CAP] | u1f[n*32] | u2f[n*32]
    char* w = (char*)d_ws;
    int*    bcursor = (int*)w;     w += (size_t)nbuck * 4;
    float*  dinv    = (float*)w;   w += (size_t)n * 4;
    int*    eb      = (int*)w;     w += (size_t)nbuck * CAP * 4;
    w = (char*)(((size_t)w + 127) & ~(size_t)127);
    float*  u1f     = (float*)w;   w += (size_t)n * 32 * 4;
    w = (char*)(((size_t)w + 127) & ~(size_t)127);
    float*  u2f     = (float*)w;   w += (size_t)n * 32 * 4;

    hipMemsetAsync(bcursor, 0, (size_t)nbuck * 4, stream);
    k_part<<<(E + CH - 1) / CH, TPB, 0, stream>>>(src, dst, bcursor, eb, E, nbuck);
    k_prep<<<nbuck, TPB, 0, stream>>>(eb, bcursor, x, dinv, u1f, n);

    k_layer1<<<nbuck, LTPB, 0, stream>>>((const float4*)u1f, eb, bcursor, dinv,
                                         W1, b1, u2f, n);
    k_layer2<<<nbuck, LTPB, 0, stream>>>((const float4*)u2f, eb, bcursor, dinv,
                                         W2, b2, Wfc, bfc, out, n);
}

// Round 14
// 180.889 us; speedup vs baseline: 3.8790x; 3.8790x over previous
//
#include <hip/hip_runtime.h>
#include <hip/hip_fp16.h>
#include <math.h>

// GCN, R14: R11 structure (slab bucket sort + padded CSR + intra-wave LDS
// hand-off), agg groups shrunk to 4 lanes/node -> 16 nodes/wave, uint4
// (8-half) gathers of 64B fp16 rows, fp32 accumulate. The R10->R11 win came
// from more node-groups/wave + fewer VMEM insts/edge; this doubles both.
// eb packed (src<<8)|(dst&255). u rows fp16, stride 32 halves = one 64B line.

#define TPB 256
#define BSH 8                 // 256 nodes per bucket
#define BNODES 256
#define MAXBUCK 512
#define CH 8192               // edges per partition block
#define CAPSH 13              // slab capacity 8192 entries/bucket
#define CAP (1 << CAPSH)

// partition edges into per-bucket slabs; bcursor RELATIVE (memset 0).
// block 0 also zeroes the dummy row n of u1h/u2h.
__global__ void k_part(const int* __restrict__ src, const int* __restrict__ dst,
                       int* __restrict__ bcursor, int* __restrict__ eb,
                       __half* __restrict__ u1h, __half* __restrict__ u2h,
                       int E, int n, int nbuck) {
    __shared__ int lh[MAXBUCK];
    __shared__ int lbase[MAXBUCK];
    int t = threadIdx.x;
    if (blockIdx.x == 0 && t < 32) {
        u1h[(size_t)n * 32 + t] = __float2half_rn(0.f);
        u2h[(size_t)n * 32 + t] = __float2half_rn(0.f);
    }
    int chunk0 = blockIdx.x * CH;
    int end = min(chunk0 + CH, E);
    const int4* dst4 = (const int4*)dst;
    const int4* src4 = (const int4*)src;
    for (int i = t; i < nbuck; i += TPB) lh[i] = 0;
    __syncthreads();
    for (int e4 = chunk0 / 4 + t; e4 * 4 < end; e4 += TPB) {
        int base = e4 * 4;
        int4 d = dst4[e4];
        if (base + 0 < end) atomicAdd(&lh[d.x >> BSH], 1);
        if (base + 1 < end) atomicAdd(&lh[d.y >> BSH], 1);
        if (base + 2 < end) atomicAdd(&lh[d.z >> BSH], 1);
        if (base + 3 < end) atomicAdd(&lh[d.w >> BSH], 1);
    }
    __syncthreads();
    for (int i = t; i < nbuck; i += TPB) {
        int c = lh[i];
        lbase[i] = c ? atomicAdd(&bcursor[i], c) : 0;
        lh[i] = 0;
    }
    __syncthreads();
    for (int e4 = chunk0 / 4 + t; e4 * 4 < end; e4 += TPB) {
        int base = e4 * 4;
        int4 d = dst4[e4];
        int4 s = src4[e4];
        #define PUT(c, sv) if (base + c < end) { \
            int b = (d.sv) >> BSH; \
            int r = lbase[b] + atomicAdd(&lh[b], 1); \
            if (r < CAP) \
                eb[((size_t)b << CAPSH) + r] = ((s.sv) << BSH) | ((d.sv) & (BNODES - 1)); }
        PUT(0, x) PUT(1, y) PUT(2, z) PUT(3, w)
        #undef PUT
    }
}

// per bucket: LDS counting sort into PADDED csr segments (4-aligned starts,
// pads = node id n -> zero row). Outputs row_start, cnt4, dinv, u1h rows.
__global__ void k_bucket(const int* __restrict__ eb, const int* __restrict__ bcursor,
                         const float* __restrict__ x,
                         int* __restrict__ csr, int* __restrict__ row_start,
                         int* __restrict__ cnt4, float* __restrict__ dinv,
                         __half* __restrict__ u1h, int n) {
    __shared__ int lcnt[BNODES];
    __shared__ int lscan[BNODES];
    __shared__ float ldinv[BNODES];
    int b = blockIdx.x;
    int t = threadIdx.x;
    int node0 = b << BSH;
    int beg = b << CAPSH;
    int end = beg + min(bcursor[b], CAP);
    lcnt[t] = 0;
    __syncthreads();
    for (int i = beg + t; i < end; i += TPB)
        atomicAdd(&lcnt[eb[i] & (BNODES - 1)], 1);
    __syncthreads();
    int v = lcnt[t];
    int pad = (v + 3) & ~3;
    lscan[t] = pad;
    __syncthreads();
    for (int off = 1; off < TPB; off <<= 1) {
        int xx = (t >= off) ? lscan[t - off] : 0;
        __syncthreads();
        lscan[t] += xx;
        __syncthreads();
    }
    int pexcl = lscan[t] - pad;
    int node = node0 + t;
    float dv = rsqrtf(1.0f + (float)v);
    ldinv[t] = dv;
    if (node < n) {
        row_start[node] = beg + pexcl;
        cnt4[node] = pad >> 2;
        dinv[node] = dv;
    }
    __syncthreads();
    lcnt[t] = pexcl;
    __syncthreads();
    for (int i = beg + t; i < end; i += TPB) {
        int e = eb[i];
        int p = atomicAdd(&lcnt[e & (BNODES - 1)], 1);
        csr[beg + p] = e >> BSH;
    }
    __syncthreads();
    for (int p = v; p < pad; ++p) csr[beg + pexcl + p] = n;
    int nn = min(BNODES, n - node0);
    int tot = nn * 32;
    const float* xb = x + (size_t)node0 * 18;
    __half* ub = u1h + (size_t)node0 * 32;
    for (int i = t; i < tot; i += TPB) {
        int nl = i >> 5, f = i & 31;
        float val = (f < 18) ? xb[nl * 18 + f] * ldinv[nl] : 0.f;
        ub[i] = __float2half_rn(val);
    }
}

#define CVTACC(vv) { \
    __half2* ph = (__half2*)&(vv); \
    float2 c0 = __half22float2(ph[0]); \
    float2 c1 = __half22float2(ph[1]); \
    float2 c2 = __half22float2(ph[2]); \
    float2 c3 = __half22float2(ph[3]); \
    a0 += c0.x; a1 += c0.y; a2 += c1.x; a3 += c1.y; \
    a4 += c2.x; a5 += c2.y; a6 += c3.x; a7 += c3.y; }

// fused layer1: agg (4 lanes/node, uint4 gathers, 16 nodes/wave) ->
// intra-wave LDS -> transform (half-wave/node, W1 col in 18 VGPRs) -> u2h.
__global__ void k_fused1(const uint4* __restrict__ u1x, const int* __restrict__ row_start,
                         const int* __restrict__ cnt4, const int* __restrict__ csr,
                         const float* __restrict__ dinv, const float* __restrict__ W1,
                         const float* __restrict__ b1, __half* __restrict__ u2h,
                         int n) {
    __shared__ float lagg[4][16][36];   // 16B-aligned rows
    int t = threadIdx.x;
    int lane = t & 63, wv = t >> 6;
    int q = lane & 3, grp = lane >> 2;      // 16 groups of 4 lanes
    int f = lane & 31, h = lane >> 5;
    float w1r[18];
#pragma unroll
    for (int k = 0; k < 18; ++k) w1r[k] = W1[k * 32 + f];
    float b1v = b1[f];
    int node0 = (blockIdx.x * 4 + wv) * 16;
    int node = node0 + grp;
    float a0 = 0.f, a1 = 0.f, a2 = 0.f, a3 = 0.f;
    float a4 = 0.f, a5 = 0.f, a6 = 0.f, a7 = 0.f;
    if (node < n) {
        uint4 sv = u1x[(size_t)node * 4 + q];
        CVTACC(sv)
        int beg = row_start[node];
        int it = cnt4[node];
        const int4* ip = (const int4*)(csr + beg);
        for (int i = 0; i < it; ++i) {
            int4 s = ip[i];
            uint4 v0 = u1x[(size_t)s.x * 4 + q];
            uint4 v1 = u1x[(size_t)s.y * 4 + q];
            uint4 v2 = u1x[(size_t)s.z * 4 + q];
            uint4 v3 = u1x[(size_t)s.w * 4 + q];
            CVTACC(v0) CVTACC(v1) CVTACC(v2) CVTACC(v3)
        }
    }
    *(float4*)&lagg[wv][grp][8 * q]     = make_float4(a0, a1, a2, a3);
    *(float4*)&lagg[wv][grp][8 * q + 4] = make_float4(a4, a5, a6, a7);
    // transform: half-wave h, 8 passes cover 16 nodes
#pragma unroll
    for (int r = 0; r < 8; ++r) {
        int nl = 2 * r + h;
        int nodeT = node0 + nl;
        if (nodeT < n) {
            const float* rp = lagg[wv][nl];
            float a = 0.f;
#pragma unroll
            for (int k = 0; k < 18; ++k) a = fmaf(rp[k], w1r[k], a);
            float di = dinv[nodeT];
            u2h[(size_t)nodeT * 32 + f] =
                __float2half_rn(fmaxf(fmaf(di, a, b1v), 0.f) * di);
        }
    }
}

// fused layer2 + head: agg (4 lanes/node) -> intra-wave LDS -> transform
// (lane = output, W2 col in 32 VGPRs) -> FC(64->2) butterfly -> log_softmax.
__global__ void k_fused2(const uint4* __restrict__ u2x, const int* __restrict__ row_start,
                         const int* __restrict__ cnt4, const int* __restrict__ csr,
                         const float* __restrict__ dinv, const float* __restrict__ W2,
                         const float* __restrict__ b2, const float* __restrict__ Wfc,
                         const float* __restrict__ bfc, float* __restrict__ out,
                         int n) {
    __shared__ float lagg[4][16][36];
    int t = threadIdx.x;
    int lane = t & 63, wv = t >> 6;
    int q = lane & 3, grp = lane >> 2;
    float w2r[32];
#pragma unroll
    for (int k = 0; k < 32; ++k) w2r[k] = W2[k * 64 + lane];
    float b2v = b2[lane];
    float wf0 = Wfc[lane * 2 + 0], wf1 = Wfc[lane * 2 + 1];
    float bf0 = bfc[0], bf1 = bfc[1];
    int node0 = (blockIdx.x * 4 + wv) * 16;
    int node = node0 + grp;
    float a0 = 0.f, a1 = 0.f, a2 = 0.f, a3 = 0.f;
    float a4 = 0.f, a5 = 0.f, a6 = 0.f, a7 = 0.f;
    if (node < n) {
        uint4 sv = u2x[(size_t)node * 4 + q];
        CVTACC(sv)
        int beg = row_start[node];
        int it = cnt4[node];
        const int4* ip = (const int4*)(csr + beg);
        for (int i = 0; i < it; ++i) {
            int4 s = ip[i];
            uint4 v0 = u2x[(size_t)s.x * 4 + q];
            uint4 v1 = u2x[(size_t)s.y * 4 + q];
            uint4 v2 = u2x[(size_t)s.z * 4 + q];
            uint4 v3 = u2x[(size_t)s.w * 4 + q];
            CVTACC(v0) CVTACC(v1) CVTACC(v2) CVTACC(v3)
        }
    }
    *(float4*)&lagg[wv][grp][8 * q]     = make_float4(a0, a1, a2, a3);
    *(float4*)&lagg[wv][grp][8 * q + 4] = make_float4(a4, a5, a6, a7);
#pragma unroll 4
    for (int r = 0; r < 16; ++r) {
        int nodeT = node0 + r;
        const float* rp = lagg[wv][r];
        float c0 = 0.f, c1 = 0.f, c2 = 0.f, c3 = 0.f;
#pragma unroll
        for (int k = 0; k < 32; k += 4) {
            c0 = fmaf(rp[k],     w2r[k],     c0);
            c1 = fmaf(rp[k + 1], w2r[k + 1], c1);
            c2 = fmaf(rp[k + 2], w2r[k + 2], c2);
            c3 = fmaf(rp[k + 3], w2r[k + 3], c3);
        }
        float a = (c0 + c1) + (c2 + c3);
        float v = (nodeT < n) ? fmaxf(fmaf(dinv[nodeT], a, b2v), 0.f) : 0.f;
        float l0 = v * wf0;
        float l1 = v * wf1;
#pragma unroll
        for (int off = 32; off >= 1; off >>= 1) {
            l0 += __shfl_xor(l0, off, 64);
            l1 += __shfl_xor(l1, off, 64);
        }
        if (lane == 0 && nodeT < n) {
            l0 += bf0;
            l1 += bf1;
            float m2 = fmaxf(l0, l1);
            float lse = m2 + logf(expf(l0 - m2) + expf(l1 - m2));
            out[nodeT * 2 + 0] = l0 - lse;
            out[nodeT * 2 + 1] = l1 - lse;
        }
    }
}

extern "C" void kernel_launch(void* const* d_in, const int* in_sizes, int n_in,
                              void* d_out, int out_size, void* d_ws, size_t ws_size,
                              hipStream_t stream) {
    const float* x   = (const float*)d_in[0];
    const int*   ei  = (const int*)d_in[1];
    const float* W1  = (const float*)d_in[2];
    const float* b1  = (const float*)d_in[3];
    const float* W2  = (const float*)d_in[4];
    const float* b2  = (const float*)d_in[5];
    const float* Wfc = (const float*)d_in[6];
    const float* bfc = (const float*)d_in[7];
    float* out = (float*)d_out;

    const int n = in_sizes[0] / 18;
    const int E = in_sizes[1] / 2;
    const int* src = ei;
    const int* dst = ei + E;
    const int nbuck = (n + BNODES - 1) >> BSH;

    // ws: bcursor[nbuck] | row_start[n] | cnt4[n] | dinv[n]
    //  | eb[nbuck*CAP] | csr[nbuck*CAP] | u1h[(n+1)*32 h] | u2h[(n+1)*32 h]
    char* w = (char*)d_ws;
    int*    bcursor   = (int*)w;     w += (size_t)nbuck * 4;
    int*    row_start = (int*)w;     w += (size_t)n * 4;
    int*    cnt4      = (int*)w;     w += (size_t)n * 4;
    float*  dinv      = (float*)w;   w += (size_t)n * 4;
    int*    eb        = (int*)w;     w += (size_t)nbuck * CAP * 4;
    int*    csr       = (int*)w;     w += (size_t)nbuck * CAP * 4;
    w = (char*)(((size_t)w + 63) & ~(size_t)63);
    __half* u1h       = (__half*)w;  w += (size_t)(n + 1) * 32 * 2;
    w = (char*)(((size_t)w + 63) & ~(size_t)63);
    __half* u2h       = (__half*)w;  w += (size_t)(n + 1) * 32 * 2;

    hipMemsetAsync(bcursor, 0, (size_t)nbuck * 4, stream);
    k_part<<<(E + CH - 1) / CH, TPB, 0, stream>>>(src, dst, bcursor, eb, u1h, u2h, E, n, nbuck);
    k_bucket<<<nbuck, TPB, 0, stream>>>(eb, bcursor, x, csr, row_start, cnt4, dinv, u1h, n);

    const int waves = (n + 15) / 16;
    const int blocksF = (waves + 3) / 4;

    k_fused1<<<blocksF, TPB, 0, stream>>>((const uint4*)u1h, row_start, cnt4, csr,
                                          dinv, W1, b1, u2h, n);
    k_fused2<<<blocksF, TPB, 0, stream>>>((const uint4*)u2h, row_start, cnt4, csr,
                                          dinv, W2, b2, Wfc, bfc, out, n);
}